// Round 4
// baseline (9568.507 us; speedup 1.0000x reference)
//
#include <hip/hip_runtime.h>

#define NN 100000
#define EE 3200000
#define EPSF 1e-5f

typedef unsigned short u16;

static inline int cdiv(int a, int b) { return (a + b - 1) / b; }

__device__ __forceinline__ float b2f(u16 u) {
    return __uint_as_float((unsigned int)u << 16);
}
__device__ __forceinline__ u16 f2b(float f) {
    unsigned int i = __float_as_uint(f);
    return (u16)((i + 0x7FFFu + ((i >> 16) & 1u)) >> 16);  // RNE
}

// ---------------- zero-init (replaces hipMemsetAsync under graph capture) ----------------
__global__ void k_init(int* __restrict__ deg, int* __restrict__ cursor,
                       float* __restrict__ stats) {
    int i = blockIdx.x * 256 + threadIdx.x;
    if (i < NN) {
        deg[i] = 0;
        cursor[i] = 0;
    }
    if (i < 2048) stats[i] = 0.f;
}

// ---------------- degree histogram ----------------
__global__ void k_deg(const int* __restrict__ col, int* __restrict__ deg) {
    int i = blockIdx.x * 256 + threadIdx.x;
    if (i < EE) atomicAdd(&deg[col[i]], 1);
}

__global__ void k_dinv(const int* __restrict__ deg, float* __restrict__ dinv) {
    int i = blockIdx.x * 256 + threadIdx.x;
    if (i < NN) {
        int d = deg[i];
        dinv[i] = d > 0 ? rsqrtf((float)d) : 0.f;
    }
}

// ---------------- exclusive scan (single block, chunked) ----------------
__global__ void k_scan(const int* __restrict__ deg, int* __restrict__ offs) {
    __shared__ int sh[1024];
    __shared__ int carry_s;
    int tid = threadIdx.x;
    if (tid == 0) carry_s = 0;
    __syncthreads();
    for (int base = 0; base < NN; base += 1024) {
        int i = base + tid;
        int v = (i < NN) ? deg[i] : 0;
        sh[tid] = v;
        __syncthreads();
        for (int off = 1; off < 1024; off <<= 1) {
            int t = (tid >= off) ? sh[tid - off] : 0;
            __syncthreads();
            sh[tid] += t;
            __syncthreads();
        }
        int carry = carry_s;
        if (i < NN) offs[i] = carry + sh[tid] - v;  // exclusive
        __syncthreads();
        if (tid == 1023) carry_s = carry + sh[1023];
        __syncthreads();
    }
    if (tid == 0) offs[NN] = carry_s;
}

// ---------------- CSR scatter (weights stored bf16) ----------------
__global__ void k_scatter(const int* __restrict__ row, const int* __restrict__ col,
                          const float* __restrict__ dinv, const int* __restrict__ offs,
                          int* __restrict__ cursor, int* __restrict__ csr_src,
                          u16* __restrict__ csr_w) {
    int i = blockIdx.x * 256 + threadIdx.x;
    if (i < EE) {
        int c = col[i], r = row[i];
        int pos = offs[c] + atomicAdd(&cursor[c], 1);
        csr_src[pos] = r;
        csr_w[pos] = f2b(dinv[r] * dinv[c]);
    }
}

// ---------------- convert x column-chunk (fp32, ld 128) -> bf16 N x 64 ----------------
__global__ void k_cvt_x(const float* __restrict__ x, int c0, u16* __restrict__ P) {
    int idx = blockIdx.x * 256 + threadIdx.x;  // over NN*16 float4s
    if (idx >= NN * 16) return;
    int node = idx >> 4, j = (idx & 15) << 2;
    float4 v = *(const float4*)(x + (size_t)node * 128 + c0 + j);
    ushort4 o;
    o.x = f2b(v.x);
    o.y = f2b(v.y);
    o.z = f2b(v.z);
    o.w = f2b(v.w);
    *(ushort4*)(P + (size_t)node * 64 + j) = o;
}

// ------- gather propagation, width = blockDim.x (bf16 in/out, fp32 acc) -------
__global__ void k_prop(const u16* __restrict__ in, int ldin, u16* __restrict__ out, int ldout,
                       const int* __restrict__ offs, const int* __restrict__ csr_src,
                       const u16* __restrict__ csr_w) {
    int i = blockIdx.x;
    int f = threadIdx.x;
    int s = offs[i], e = offs[i + 1];
    float acc = 0.f;
    for (int t = s; t < e; ++t)
        acc = fmaf(b2f(csr_w[t]), b2f(in[(size_t)csr_src[t] * ldin + f]), acc);
    out[(size_t)i * ldout + f] = f2b(acc);
}

// ---------------- width-16 fp32 propagation with addend (Horner) ----------------
__global__ void k_prop16(const float* __restrict__ in, int ldin,
                         const float* __restrict__ add, int ldadd,
                         float* __restrict__ out, const float* __restrict__ bias,
                         const int* __restrict__ offs, const int* __restrict__ csr_src,
                         const u16* __restrict__ csr_w) {
    int node = blockIdx.x * 16 + (threadIdx.x >> 4);
    if (node >= NN) return;
    int f = threadIdx.x & 15;
    float acc = add[(size_t)node * ldadd + f];
    int s = offs[node], e = offs[node + 1];
    for (int t = s; t < e; ++t)
        acc = fmaf(b2f(csr_w[t]), in[(size_t)csr_src[t] * ldin + f], acc);
    if (bias) acc += bias[f];
    out[node * 16 + f] = acc;
}

// ---- tiled GEMM: A bf16 (MxK), B fp32 (KxN), 64x64 tile.
// cmode: 0 = write fp32, 1 = write bf16 fresh, 2 = accumulate into bf16 C ----
__global__ __launch_bounds__(256) void k_gemm(const u16* __restrict__ A, int lda,
                                              const float* __restrict__ B, int ldb,
                                              void* __restrict__ Cv, int ldc, int M, int K,
                                              const float* __restrict__ bias, int relu,
                                              int cmode) {
    __shared__ float As[16][68];
    __shared__ float Bs[16][68];
    int tid = threadIdx.x;
    int bx = blockIdx.x, by = blockIdx.y;
    int tx = tid & 15, ty = tid >> 4;
    float acc[4][4] = {};
    int ar = tid >> 2;         // 0..63 (M row in tile)
    int akq = (tid & 3) << 2;  // 0,4,8,12 (k quad)
    int grow = by * 64 + ar;
    int kb = tid >> 4;         // 0..15
    int nb = (tid & 15) << 2;  // 0..60
    const int gcol = bx * 64;

    for (int kt = 0; kt < K; kt += 16) {
        ushort4 av;
        av.x = av.y = av.z = av.w = 0;
        if (grow < M) av = *(const ushort4*)(A + (size_t)grow * lda + kt + akq);
        As[akq + 0][ar] = b2f(av.x);
        As[akq + 1][ar] = b2f(av.y);
        As[akq + 2][ar] = b2f(av.z);
        As[akq + 3][ar] = b2f(av.w);
        float4 bv = *(const float4*)(B + (size_t)(kt + kb) * ldb + gcol + nb);
        *(float4*)&Bs[kb][nb] = bv;
        __syncthreads();
#pragma unroll
        for (int kk = 0; kk < 16; ++kk) {
            float4 a = *(float4*)&As[kk][ty << 2];
            float4 b = *(float4*)&Bs[kk][tx << 2];
            float ar_[4] = {a.x, a.y, a.z, a.w};
            float br_[4] = {b.x, b.y, b.z, b.w};
#pragma unroll
            for (int i = 0; i < 4; ++i)
#pragma unroll
                for (int j = 0; j < 4; ++j)
                    acc[i][j] = fmaf(ar_[i], br_[j], acc[i][j]);
        }
        __syncthreads();
    }
#pragma unroll
    for (int i = 0; i < 4; ++i) {
        int r = by * 64 + (ty << 2) + i;
        if (r >= M) continue;
        float t[4];
        if (cmode == 2) {
            ushort4 o = *(ushort4*)((u16*)Cv + (size_t)r * ldc + gcol + (tx << 2));
            t[0] = acc[i][0] + b2f(o.x);
            t[1] = acc[i][1] + b2f(o.y);
            t[2] = acc[i][2] + b2f(o.z);
            t[3] = acc[i][3] + b2f(o.w);
        } else {
#pragma unroll
            for (int j = 0; j < 4; ++j) t[j] = acc[i][j];
        }
#pragma unroll
        for (int j = 0; j < 4; ++j) {
            int c = gcol + (tx << 2) + j;
            if (bias) t[j] += bias[c];
            if (relu) t[j] = fmaxf(t[j], 0.f);
        }
        if (cmode == 0) {
            float4 v = make_float4(t[0], t[1], t[2], t[3]);
            *(float4*)((float*)Cv + (size_t)r * ldc + gcol + (tx << 2)) = v;
        } else {
            ushort4 w;
            w.x = f2b(t[0]);
            w.y = f2b(t[1]);
            w.z = f2b(t[2]);
            w.w = f2b(t[3]);
            *(ushort4*)((u16*)Cv + (size_t)r * ldc + gcol + (tx << 2)) = w;
        }
    }
}

// ---------------- column stats (sum, sumsq) over bf16 NNx512 ----------------
__global__ void k_colstats(const u16* __restrict__ X, int ld, float* __restrict__ stats) {
    int r0 = blockIdx.x * 64;
    int c = threadIdx.x * 2;
    float s0 = 0, s1 = 0, q0 = 0, q1 = 0;
    int rend = min(r0 + 64, NN);
    for (int r = r0; r < rend; ++r) {
        ushort2 v = *(const ushort2*)(X + (size_t)r * ld + c);
        float x0 = b2f(v.x), x1 = b2f(v.y);
        s0 += x0;
        s1 += x1;
        q0 += x0 * x0;
        q1 += x1 * x1;
    }
    atomicAdd(&stats[c], s0);
    atomicAdd(&stats[c + 1], s1);
    atomicAdd(&stats[512 + c], q0);
    atomicAdd(&stats[512 + c + 1], q1);
}

// ---------------- graphnorm apply (in place, bf16) ----------------
__global__ void k_gnorm(u16* __restrict__ X, int ld, const float* __restrict__ stats,
                        const float* __restrict__ w, const float* __restrict__ b,
                        const float* __restrict__ a) {
    int i = blockIdx.x;
    int c = threadIdx.x * 2;
    const float invn = 1.f / NN;
    ushort2 v = *(ushort2*)(X + (size_t)i * ld + c);
    float x0 = b2f(v.x), x1 = b2f(v.y);
    {
        float m = stats[c] * invn, q = stats[512 + c] * invn, al = a[c];
        float var = q - (2.f * al - al * al) * m * m;
        x0 = (x0 - al * m) * rsqrtf(var + EPSF) * w[c] + b[c];
    }
    {
        int c1 = c + 1;
        float m = stats[c1] * invn, q = stats[512 + c1] * invn, al = a[c1];
        float var = q - (2.f * al - al * al) * m * m;
        x1 = (x1 - al * m) * rsqrtf(var + EPSF) * w[c1] + b[c1];
    }
    v.x = f2b(x0);
    v.y = f2b(x1);
    *(ushort2*)(X + (size_t)i * ld + c) = v;
}

// ---------------- repack W3 (4,512,16) -> (512,64) column-concat ----------------
__global__ void k_repackW3(const float* __restrict__ W3, float* __restrict__ W3c) {
    int idx = blockIdx.x * 256 + threadIdx.x;
    if (idx >= 512 * 64) return;
    int kk = idx >> 6, c = idx & 63, k = c >> 4, f = c & 15;
    W3c[idx] = W3[((size_t)k * 512 + kk) * 16 + f];
}

extern "C" void kernel_launch(void* const* d_in, const int* in_sizes, int n_in,
                              void* d_out, int out_size, void* d_ws, size_t ws_size,
                              hipStream_t stream) {
    const float* x = (const float*)d_in[0];
    const int* ei = (const int*)d_in[1];
    const float* W1 = (const float*)d_in[2];
    const float* b1 = (const float*)d_in[3];
    const float* W2 = (const float*)d_in[4];
    const float* b2 = (const float*)d_in[5];
    const float* W3 = (const float*)d_in[6];
    const float* b3 = (const float*)d_in[7];
    const float* g1w = (const float*)d_in[8];
    const float* g1b = (const float*)d_in[9];
    const float* g1a = (const float*)d_in[10];
    const float* g2w = (const float*)d_in[11];
    const float* g2b = (const float*)d_in[12];
    const float* g2a = (const float*)d_in[13];
    const int* row = ei;
    const int* col = ei + EE;

    char* p = (char*)d_ws;
    auto alloc = [&](size_t bytes) {
        char* r = p;
        p += (bytes + 255) & ~(size_t)255;
        return r;
    };
    // Total workspace: ~239.7 MiB (kept under a presumed 256 MiB budget)
    u16* H1 = (u16*)alloc((size_t)NN * 512 * 2);  // 102.4 MB: L1 acc -> h1 -> (fp32) L3 G
    u16* Y = (u16*)alloc((size_t)NN * 512 * 2);   // 102.4 MB: L2 acc -> h2
    u16* P0 = (u16*)alloc((size_t)NN * 64 * 2);   // 12.8 MB hop ping / (fp32) L3 tA
    u16* P1 = (u16*)alloc((size_t)NN * 64 * 2);   // 12.8 MB hop pong / (fp32) L3 tB
    int* csrs = (int*)alloc((size_t)EE * 4);      // 12.8 MB
    u16* csrw = (u16*)alloc((size_t)EE * 2);      // 6.4 MB
    float* dinv = (float*)alloc((size_t)NN * 4);
    float* W3c = (float*)alloc(512 * 64 * 4);
    float* stats = (float*)alloc(2048 * 4);  // [sum1|sq1|sum2|sq2]
    int* deg = (int*)alloc((size_t)NN * 4);
    int* offs = (int*)alloc((size_t)(NN + 1) * 4);
    int* cursor = (int*)alloc((size_t)NN * 4);
    (void)ws_size;
    (void)in_sizes;
    (void)n_in;
    (void)out_size;

    // CSR build (no hipMemsetAsync — zero via kernel to be graph-capture-safe)
    k_init<<<cdiv(NN, 256), 256, 0, stream>>>(deg, cursor, stats);
    k_deg<<<cdiv(EE, 256), 256, 0, stream>>>(col, deg);
    k_dinv<<<cdiv(NN, 256), 256, 0, stream>>>(deg, dinv);
    k_scan<<<1, 1024, 0, stream>>>(deg, offs);
    k_scatter<<<cdiv(EE, 256), 256, 0, stream>>>(row, col, dinv, offs, cursor, csrs, csrw);

    dim3 g512(512 / 64, cdiv(NN, 64));

    // ---- layer 1: H1 = sum_k (A^k x) W1[k], K-chunked by 64 (2 chunks); relu+gnorm
    for (int c = 0; c < 2; ++c) {
        const float* W1c = W1 + (size_t)c * 64 * 512;  // rows 64c.. of W1[k] at +k*128*512
        k_cvt_x<<<cdiv(NN * 16, 256), 256, 0, stream>>>(x, c * 64, P0);
        k_gemm<<<g512, 256, 0, stream>>>(P0, 64, W1c, 512, H1, 512, NN, 64, nullptr, 0,
                                         c == 0 ? 1 : 2);
        k_prop<<<NN, 64, 0, stream>>>(P0, 64, P1, 64, offs, csrs, csrw);
        k_gemm<<<g512, 256, 0, stream>>>(P1, 64, W1c + (size_t)1 * 128 * 512, 512, H1, 512, NN,
                                         64, nullptr, 0, 2);
        k_prop<<<NN, 64, 0, stream>>>(P1, 64, P0, 64, offs, csrs, csrw);
        k_gemm<<<g512, 256, 0, stream>>>(P0, 64, W1c + (size_t)2 * 128 * 512, 512, H1, 512, NN,
                                         64, nullptr, 0, 2);
        k_prop<<<NN, 64, 0, stream>>>(P0, 64, P1, 64, offs, csrs, csrw);
        k_gemm<<<g512, 256, 0, stream>>>(P1, 64, W1c + (size_t)3 * 128 * 512, 512, H1, 512, NN,
                                         64, (c == 1) ? b1 : nullptr, c == 1 ? 1 : 0, 2);
    }
    k_colstats<<<cdiv(NN, 64), 256, 0, stream>>>(H1, 512, stats);
    k_gnorm<<<NN, 256, 0, stream>>>(H1, 512, stats, g1w, g1b, g1a);

    // ---- layer 2: Y = sum_k (A^k h1) W2[k], K-chunked by 64 (8 chunks); relu+gnorm
    for (int c = 0; c < 8; ++c) {
        const float* W2c = W2 + (size_t)c * 64 * 512;  // rows 64c.. of W2[k] at +k*512*512
        const u16* h1c = H1 + c * 64;
        int last = (c == 7);
        k_gemm<<<g512, 256, 0, stream>>>(h1c, 512, W2c, 512, Y, 512, NN, 64, nullptr, 0,
                                         c == 0 ? 1 : 2);
        k_prop<<<NN, 64, 0, stream>>>(h1c, 512, P1, 64, offs, csrs, csrw);
        k_gemm<<<g512, 256, 0, stream>>>(P1, 64, W2c + (size_t)1 * 512 * 512, 512, Y, 512, NN,
                                         64, nullptr, 0, 2);
        k_prop<<<NN, 64, 0, stream>>>(P1, 64, P0, 64, offs, csrs, csrw);
        k_gemm<<<g512, 256, 0, stream>>>(P0, 64, W2c + (size_t)2 * 512 * 512, 512, Y, 512, NN,
                                         64, nullptr, 0, 2);
        k_prop<<<NN, 64, 0, stream>>>(P0, 64, P1, 64, offs, csrs, csrw);
        k_gemm<<<g512, 256, 0, stream>>>(P1, 64, W2c + (size_t)3 * 512 * 512, 512, Y, 512, NN,
                                         64, last ? b2 : nullptr, last ? 1 : 0, 2);
    }
    k_colstats<<<cdiv(NN, 64), 256, 0, stream>>>(Y, 512, stats + 1024);
    k_gnorm<<<NN, 256, 0, stream>>>(Y, 512, stats + 1024, g2w, g2b, g2a);

    // ---- layer 3 (Horner at width 16): G = h2 @ [W3_0|W3_1|W3_2|W3_3] (fp32, overlays H1)
    float* G = (float*)H1;    // NN x 64 fp32 = 25.6 MB <= 102.4 MB
    float* tA = (float*)P0;   // NN x 16 fp32 = 6.4 MB <= 12.8 MB
    float* tB = (float*)P1;
    k_repackW3<<<cdiv(512 * 64, 256), 256, 0, stream>>>(W3, W3c);
    {
        dim3 g(1, cdiv(NN, 64));
        k_gemm<<<g, 256, 0, stream>>>(Y, 512, W3c, 64, G, 64, NN, 512, nullptr, 0, 0);
    }
    k_prop16<<<cdiv(NN, 16), 256, 0, stream>>>(G + 48, 64, G + 32, 64, tA, nullptr, offs, csrs,
                                               csrw);
    k_prop16<<<cdiv(NN, 16), 256, 0, stream>>>(tA, 16, G + 16, 64, tB, nullptr, offs, csrs, csrw);
    k_prop16<<<cdiv(NN, 16), 256, 0, stream>>>(tB, 16, G + 0, 64, (float*)d_out, b3, offs, csrs,
                                               csrw);
}

// Round 5
// 4862.220 us; speedup vs baseline: 1.9679x; 1.9679x over previous
//
#include <hip/hip_runtime.h>

#define NN 100000
#define EE 3200000
#define EPSF 1e-5f

typedef unsigned short u16;
typedef short bf16x8 __attribute__((ext_vector_type(8)));
typedef float f32x4 __attribute__((ext_vector_type(4)));

static inline int cdiv(int a, int b) { return (a + b - 1) / b; }

__device__ __forceinline__ float b2f(u16 u) {
    return __uint_as_float((unsigned int)u << 16);
}
__device__ __forceinline__ u16 f2b(float f) {
    unsigned int i = __float_as_uint(f);
    return (u16)((i + 0x7FFFu + ((i >> 16) & 1u)) >> 16);  // RNE
}

// ---------------- zero-init (graph-capture-safe) ----------------
__global__ void k_init(int* __restrict__ deg, int* __restrict__ cursor,
                       float* __restrict__ stats) {
    int i = blockIdx.x * 256 + threadIdx.x;
    if (i < NN) {
        deg[i] = 0;
        cursor[i] = 0;
    }
    if (i < 2048) stats[i] = 0.f;
}

// ---------------- degree histogram ----------------
__global__ void k_deg(const int* __restrict__ col, int* __restrict__ deg) {
    int i = blockIdx.x * 256 + threadIdx.x;
    if (i < EE) atomicAdd(&deg[col[i]], 1);
}

__global__ void k_dinv(const int* __restrict__ deg, float* __restrict__ dinv) {
    int i = blockIdx.x * 256 + threadIdx.x;
    if (i < NN) {
        int d = deg[i];
        dinv[i] = d > 0 ? rsqrtf((float)d) : 0.f;
    }
}

// ---------------- exclusive scan (single block, chunked) ----------------
__global__ void k_scan(const int* __restrict__ deg, int* __restrict__ offs) {
    __shared__ int sh[1024];
    __shared__ int carry_s;
    int tid = threadIdx.x;
    if (tid == 0) carry_s = 0;
    __syncthreads();
    for (int base = 0; base < NN; base += 1024) {
        int i = base + tid;
        int v = (i < NN) ? deg[i] : 0;
        sh[tid] = v;
        __syncthreads();
        for (int off = 1; off < 1024; off <<= 1) {
            int t = (tid >= off) ? sh[tid - off] : 0;
            __syncthreads();
            sh[tid] += t;
            __syncthreads();
        }
        int carry = carry_s;
        if (i < NN) offs[i] = carry + sh[tid] - v;  // exclusive
        __syncthreads();
        if (tid == 1023) carry_s = carry + sh[1023];
        __syncthreads();
    }
    if (tid == 0) offs[NN] = carry_s;
}

// ---------------- CSR scatter (weights stored bf16) ----------------
__global__ void k_scatter(const int* __restrict__ row, const int* __restrict__ col,
                          const float* __restrict__ dinv, const int* __restrict__ offs,
                          int* __restrict__ cursor, int* __restrict__ csr_src,
                          u16* __restrict__ csr_w) {
    int i = blockIdx.x * 256 + threadIdx.x;
    if (i < EE) {
        int c = col[i], r = row[i];
        int pos = offs[c] + atomicAdd(&cursor[c], 1);
        csr_src[pos] = r;
        csr_w[pos] = f2b(dinv[r] * dinv[c]);
    }
}

// ---------------- convert x (fp32 NNx128) -> bf16 NNx128 ----------------
__global__ void k_cvt_x(const float* __restrict__ x, u16* __restrict__ P) {
    int idx = blockIdx.x * 256 + threadIdx.x;
    if (idx >= NN * 32) return;
    float4 v = ((const float4*)x)[idx];
    ushort4 o;
    o.x = f2b(v.x);
    o.y = f2b(v.y);
    o.z = f2b(v.z);
    o.w = f2b(v.w);
    ((ushort4*)P)[idx] = o;
}

// ------- gather propagation, width 128 (bf16 in/out, fp32 acc), 64 thr/node -------
__global__ void k_prop(const u16* __restrict__ in, int ldin, u16* __restrict__ out, int ldout,
                       const int* __restrict__ offs, const int* __restrict__ csr_src,
                       const u16* __restrict__ csr_w) {
    int node = blockIdx.x;
    int f = threadIdx.x;  // 0..63 -> cols 2f, 2f+1
    int s = offs[node], e = offs[node + 1];
    float a0 = 0.f, a1 = 0.f;
    for (int t = s; t < e; ++t) {
        int src = csr_src[t];
        float w = b2f(csr_w[t]);
        ushort2 v = *(const ushort2*)(in + (size_t)src * ldin + 2 * f);
        a0 = fmaf(w, b2f(v.x), a0);
        a1 = fmaf(w, b2f(v.y), a1);
    }
    ushort2 o;
    o.x = f2b(a0);
    o.y = f2b(a1);
    *(ushort2*)(out + (size_t)node * ldout + 2 * f) = o;
}

// ---------------- width-16 fp32 propagation with addend (Horner) ----------------
__global__ void k_prop16(const float* __restrict__ in, int ldin,
                         const float* __restrict__ add, int ldadd,
                         float* __restrict__ out, const float* __restrict__ bias,
                         const int* __restrict__ offs, const int* __restrict__ csr_src,
                         const u16* __restrict__ csr_w) {
    int node = blockIdx.x * 16 + (threadIdx.x >> 4);
    if (node >= NN) return;
    int f = threadIdx.x & 15;
    float acc = add[(size_t)node * ldadd + f];
    int s = offs[node], e = offs[node + 1];
    for (int t = s; t < e; ++t)
        acc = fmaf(b2f(csr_w[t]), in[(size_t)csr_src[t] * ldin + f], acc);
    if (bias) acc += bias[f];
    out[node * 16 + f] = acc;
}

// ---- MFMA bf16 GEMM, 128x64 tile, two A/B sources (K halves).
// C = [C +] concat(A0,A1) @ concat(B0,B1); A bf16, B fp32 (converted on stage).
// cmode: 0 = write fp32, 1 = write bf16 fresh, 2 = accumulate into bf16 C ----
#define LDS_LD 40  // LDS row stride in elems (16B-aligned rows, conflict-padded)
__global__ __launch_bounds__(256) void k_gemm_mfma(
    const u16* __restrict__ A0, int lda0, const u16* __restrict__ A1, int lda1,
    const float* __restrict__ B0, const float* __restrict__ B1, int ldb,
    void* __restrict__ Cv, int ldc, int M, int Ktot, int Kh,
    const float* __restrict__ bias, int relu, int cmode) {
    __shared__ u16 As[128 * LDS_LD];
    __shared__ u16 Bs[64 * LDS_LD];
    int tid = threadIdx.x;
    int wave = tid >> 6, lane = tid & 63;
    int quad = lane >> 4, lq = lane & 15;
    int m0 = blockIdx.y * 128, n0 = blockIdx.x * 64;
    f32x4 acc[2][4] = {};

    for (int ks = 0; ks < Ktot; ks += 32) {
        const u16* Ap;
        const float* Bp;
        int lda, kk;
        if (ks < Kh) {
            Ap = A0;
            Bp = B0;
            lda = lda0;
            kk = ks;
        } else {
            Ap = A1;
            Bp = B1;
            lda = lda1;
            kk = ks - Kh;
        }
        // stage A: 128 rows x 32 k (bf16), 512 slots of 8 elems, 2 per thread
#pragma unroll
        for (int i = 0; i < 2; ++i) {
            int s = tid + i * 256;
            int r = s >> 2, ko = (s & 3) << 3;
            int gr = m0 + r;
            if (gr > M - 1) gr = M - 1;  // clamp; garbage only affects unwritten rows
            uint4 v = *(const uint4*)(Ap + (size_t)gr * lda + kk + ko);
            *(uint4*)&As[r * LDS_LD + ko] = v;
        }
        // stage B: 32 k-rows x 64 n (fp32 -> bf16, transposed to Bs[n][k])
#pragma unroll
        for (int i = 0; i < 2; ++i) {
            int s = tid + i * 256;
            int kr = s >> 4, nq = (s & 15) << 2;
            float4 bv = *(const float4*)(Bp + (size_t)(kk + kr) * ldb + n0 + nq);
            Bs[(nq + 0) * LDS_LD + kr] = f2b(bv.x);
            Bs[(nq + 1) * LDS_LD + kr] = f2b(bv.y);
            Bs[(nq + 2) * LDS_LD + kr] = f2b(bv.z);
            Bs[(nq + 3) * LDS_LD + kr] = f2b(bv.w);
        }
        __syncthreads();
        bf16x8 af[2], bfr[4];
#pragma unroll
        for (int i = 0; i < 2; ++i)
            af[i] = *(bf16x8*)&As[(wave * 32 + i * 16 + lq) * LDS_LD + quad * 8];
#pragma unroll
        for (int j = 0; j < 4; ++j)
            bfr[j] = *(bf16x8*)&Bs[(j * 16 + lq) * LDS_LD + quad * 8];
#pragma unroll
        for (int i = 0; i < 2; ++i)
#pragma unroll
            for (int j = 0; j < 4; ++j)
                acc[i][j] = __builtin_amdgcn_mfma_f32_16x16x32_bf16(af[i], bfr[j], acc[i][j],
                                                                    0, 0, 0);
        __syncthreads();
    }
    // epilogue: C/D layout col = lane&15, row = quad*4 + reg
#pragma unroll
    for (int i = 0; i < 2; ++i) {
#pragma unroll
        for (int j = 0; j < 4; ++j) {
            int c = n0 + j * 16 + lq;
            float bcol = bias ? bias[c] : 0.f;
            int rbase = m0 + wave * 32 + i * 16 + quad * 4;
#pragma unroll
            for (int reg = 0; reg < 4; ++reg) {
                int r = rbase + reg;
                if (r >= M) continue;
                float t = acc[i][j][reg];
                if (cmode == 2) t += b2f(*((u16*)Cv + (size_t)r * ldc + c));
                t += bcol;
                if (relu) t = fmaxf(t, 0.f);
                if (cmode == 0)
                    ((float*)Cv)[(size_t)r * ldc + c] = t;
                else
                    *((u16*)Cv + (size_t)r * ldc + c) = f2b(t);
            }
        }
    }
}

// ---------------- column stats (sum, sumsq) over bf16 NNx512 ----------------
__global__ void k_colstats(const u16* __restrict__ X, int ld, float* __restrict__ stats) {
    int r0 = blockIdx.x * 64;
    int c = threadIdx.x * 2;
    float s0 = 0, s1 = 0, q0 = 0, q1 = 0;
    int rend = min(r0 + 64, NN);
    for (int r = r0; r < rend; ++r) {
        ushort2 v = *(const ushort2*)(X + (size_t)r * ld + c);
        float x0 = b2f(v.x), x1 = b2f(v.y);
        s0 += x0;
        s1 += x1;
        q0 += x0 * x0;
        q1 += x1 * x1;
    }
    atomicAdd(&stats[c], s0);
    atomicAdd(&stats[c + 1], s1);
    atomicAdd(&stats[512 + c], q0);
    atomicAdd(&stats[512 + c + 1], q1);
}

// ---------------- graphnorm apply (in place, bf16) ----------------
__global__ void k_gnorm(u16* __restrict__ X, int ld, const float* __restrict__ stats,
                        const float* __restrict__ w, const float* __restrict__ b,
                        const float* __restrict__ a) {
    int i = blockIdx.x;
    int c = threadIdx.x * 2;
    const float invn = 1.f / NN;
    ushort2 v = *(ushort2*)(X + (size_t)i * ld + c);
    float x0 = b2f(v.x), x1 = b2f(v.y);
    {
        float m = stats[c] * invn, q = stats[512 + c] * invn, al = a[c];
        float var = q - (2.f * al - al * al) * m * m;
        x0 = (x0 - al * m) * rsqrtf(var + EPSF) * w[c] + b[c];
    }
    {
        int c1 = c + 1;
        float m = stats[c1] * invn, q = stats[512 + c1] * invn, al = a[c1];
        float var = q - (2.f * al - al * al) * m * m;
        x1 = (x1 - al * m) * rsqrtf(var + EPSF) * w[c1] + b[c1];
    }
    v.x = f2b(x0);
    v.y = f2b(x1);
    *(ushort2*)(X + (size_t)i * ld + c) = v;
}

// ---------------- repack W3 (4,512,16) -> (512,64) column-concat ----------------
__global__ void k_repackW3(const float* __restrict__ W3, float* __restrict__ W3c) {
    int idx = blockIdx.x * 256 + threadIdx.x;
    if (idx >= 512 * 64) return;
    int kk = idx >> 6, c = idx & 63, k = c >> 4, f = c & 15;
    W3c[idx] = W3[((size_t)k * 512 + kk) * 16 + f];
}

extern "C" void kernel_launch(void* const* d_in, const int* in_sizes, int n_in,
                              void* d_out, int out_size, void* d_ws, size_t ws_size,
                              hipStream_t stream) {
    const float* x = (const float*)d_in[0];
    const int* ei = (const int*)d_in[1];
    const float* W1 = (const float*)d_in[2];
    const float* b1 = (const float*)d_in[3];
    const float* W2 = (const float*)d_in[4];
    const float* b2 = (const float*)d_in[5];
    const float* W3 = (const float*)d_in[6];
    const float* b3 = (const float*)d_in[7];
    const float* g1w = (const float*)d_in[8];
    const float* g1b = (const float*)d_in[9];
    const float* g1a = (const float*)d_in[10];
    const float* g2w = (const float*)d_in[11];
    const float* g2b = (const float*)d_in[12];
    const float* g2a = (const float*)d_in[13];
    const int* row = ei;
    const int* col = ei + EE;

    char* p = (char*)d_ws;
    auto alloc = [&](size_t bytes) {
        char* r = p;
        p += (bytes + 255) & ~(size_t)255;
        return r;
    };
    // Total workspace ~239.8 MiB (same as round-4's proven budget)
    u16* H1 = (u16*)alloc((size_t)NN * 512 * 2);  // 102.4 MB: h1; L2 overwrites chunks w/ hop2
    u16* Y = (u16*)alloc((size_t)NN * 512 * 2);   // 102.4 MB: L1 hop scratch -> L2 acc -> h2
    u16* X = (u16*)alloc((size_t)NN * 128 * 2);   // 25.6 MB hop ping
    int* csrs = (int*)alloc((size_t)EE * 4);      // 12.8 MB
    u16* csrw = (u16*)alloc((size_t)EE * 2);      // 6.4 MB
    float* dinv = (float*)alloc((size_t)NN * 4);
    float* W3c = (float*)alloc(512 * 64 * 4);
    float* stats = (float*)alloc(2048 * 4);  // [sum1|sq1|sum2|sq2]
    int* deg = (int*)alloc((size_t)NN * 4);
    int* offs = (int*)alloc((size_t)(NN + 1) * 4);
    int* cursor = (int*)alloc((size_t)NN * 4);
    (void)ws_size;
    (void)in_sizes;
    (void)n_in;
    (void)out_size;

    u16* Yp = Y;  // L1 hop scratch region (N x 128, ld 128) inside Y

    // ---- CSR build
    k_init<<<cdiv(NN, 256), 256, 0, stream>>>(deg, cursor, stats);
    k_deg<<<cdiv(EE, 256), 256, 0, stream>>>(col, deg);
    k_dinv<<<cdiv(NN, 256), 256, 0, stream>>>(deg, dinv);
    k_scan<<<1, 1024, 0, stream>>>(deg, offs);
    k_scatter<<<cdiv(EE, 256), 256, 0, stream>>>(row, col, dinv, offs, cursor, csrs, csrw);

    dim3 gg(512 / 64, cdiv(NN, 128));  // (8, 782)

    // ---- layer 1: H1 = sum_k (A^k x) W1[k]  (hops paired 2-per-GEMM, K=256 each)
    k_cvt_x<<<cdiv(NN * 32, 256), 256, 0, stream>>>(x, X);           // X = bf16(x), hop0
    k_prop<<<NN, 64, 0, stream>>>(X, 128, Yp, 128, offs, csrs, csrw);  // Yp = hop1
    k_gemm_mfma<<<gg, 256, 0, stream>>>(X, 128, Yp, 128, W1, W1 + (size_t)1 * 128 * 512, 512,
                                        H1, 512, NN, 256, 128, nullptr, 0, 1);
    k_prop<<<NN, 64, 0, stream>>>(Yp, 128, X, 128, offs, csrs, csrw);  // X = hop2
    k_prop<<<NN, 64, 0, stream>>>(X, 128, Yp, 128, offs, csrs, csrw);  // Yp = hop3
    k_gemm_mfma<<<gg, 256, 0, stream>>>(X, 128, Yp, 128, W1 + (size_t)2 * 128 * 512,
                                        W1 + (size_t)3 * 128 * 512, 512, H1, 512, NN, 256, 128,
                                        b1, 1, 2);
    k_colstats<<<cdiv(NN, 64), 256, 0, stream>>>(H1, 512, stats);
    k_gnorm<<<NN, 256, 0, stream>>>(H1, 512, stats, g1w, g1b, g1a);

    // ---- layer 2: Y = sum_k (A^k h1) W2[k], column-chunked by 128 (4 chunks)
    for (int c = 0; c < 4; ++c) {
        u16* h1c = H1 + 128 * c;                         // ld 512
        const float* W2c = W2 + (size_t)128 * c * 512;   // rows 128c of W2[k] at +k*512*512
        k_prop<<<NN, 64, 0, stream>>>(h1c, 512, X, 128, offs, csrs, csrw);  // X = hop1
        k_gemm_mfma<<<gg, 256, 0, stream>>>(h1c, 512, X, 128, W2c,
                                            W2c + (size_t)1 * 512 * 512, 512, Y, 512, NN, 256,
                                            128, nullptr, 0, c == 0 ? 1 : 2);
        k_prop<<<NN, 64, 0, stream>>>(X, 128, h1c, 512, offs, csrs, csrw);  // h1c = hop2
        k_prop<<<NN, 64, 0, stream>>>(h1c, 512, X, 128, offs, csrs, csrw);  // X = hop3
        k_gemm_mfma<<<gg, 256, 0, stream>>>(h1c, 512, X, 128, W2c + (size_t)2 * 512 * 512,
                                            W2c + (size_t)3 * 512 * 512, 512, Y, 512, NN, 256,
                                            128, (c == 3) ? b2 : nullptr, c == 3 ? 1 : 0, 2);
    }
    k_colstats<<<cdiv(NN, 64), 256, 0, stream>>>(Y, 512, stats + 1024);
    k_gnorm<<<NN, 256, 0, stream>>>(Y, 512, stats + 1024, g2w, g2b, g2a);

    // ---- layer 3 (Horner at width 16): G = h2 @ [W3_0|W3_1|W3_2|W3_3] (fp32, overlays H1)
    float* G = (float*)H1;   // NN x 64 fp32 = 25.6 MB
    float* tA = (float*)X;   // NN x 16 fp32 = 6.4 MB
    float* tB = tA + (size_t)NN * 16;  // X is 25.6 MB, fits both
    k_repackW3<<<cdiv(512 * 64, 256), 256, 0, stream>>>(W3, W3c);
    {
        dim3 g3(1, cdiv(NN, 128));
        k_gemm_mfma<<<g3, 256, 0, stream>>>(Y, 512, Y, 512, W3c, W3c, 64, G, 64, NN, 512, 512,
                                            nullptr, 0, 0);
    }
    k_prop16<<<cdiv(NN, 16), 256, 0, stream>>>(G + 48, 64, G + 32, 64, tA, nullptr, offs, csrs,
                                               csrw);
    k_prop16<<<cdiv(NN, 16), 256, 0, stream>>>(tA, 16, G + 16, 64, tB, nullptr, offs, csrs, csrw);
    k_prop16<<<cdiv(NN, 16), 256, 0, stream>>>(tB, 16, G + 0, 64, (float*)d_out, b3, offs, csrs,
                                               csrw);
}

// Round 6
// 3733.158 us; speedup vs baseline: 2.5631x; 1.3024x over previous
//
#include <hip/hip_runtime.h>

#define NN 100000
#define EE 3200000
#define EPSF 1e-5f

typedef unsigned short u16;
typedef short bf16x8 __attribute__((ext_vector_type(8)));
typedef float f32x4 __attribute__((ext_vector_type(4)));

static inline int cdiv(int a, int b) { return (a + b - 1) / b; }

__device__ __forceinline__ float b2f(u16 u) {
    return __uint_as_float((unsigned int)u << 16);
}
__device__ __forceinline__ u16 f2b(float f) {
    unsigned int i = __float_as_uint(f);
    return (u16)((i + 0x7FFFu + ((i >> 16) & 1u)) >> 16);  // RNE
}
// unpack packed edge: [31:17] = positive float top bits, [16:0] = src index
__device__ __forceinline__ int ep_src(unsigned int p) { return (int)(p & 0x1FFFFu); }
__device__ __forceinline__ float ep_w(unsigned int p) {
    return __uint_as_float(p & 0xFFFE0000u);
}

// ---------------- zero-init (graph-capture-safe) ----------------
__global__ void k_init(int* __restrict__ deg, int* __restrict__ cursor,
                       float* __restrict__ stats) {
    int i = blockIdx.x * 256 + threadIdx.x;
    if (i < NN) {
        deg[i] = 0;
        cursor[i] = 0;
    }
    if (i < 2048) stats[i] = 0.f;
}

// ---------------- degree histogram ----------------
__global__ void k_deg(const int* __restrict__ col, int* __restrict__ deg) {
    int i = blockIdx.x * 256 + threadIdx.x;
    if (i < EE) atomicAdd(&deg[col[i]], 1);
}

__global__ void k_dinv(const int* __restrict__ deg, float* __restrict__ dinv) {
    int i = blockIdx.x * 256 + threadIdx.x;
    if (i < NN) {
        int d = deg[i];
        dinv[i] = d > 0 ? rsqrtf((float)d) : 0.f;
    }
}

// ------- exclusive scan: 1024 threads, 98 contiguous elems per thread -------
__global__ void k_scan(const int* __restrict__ deg, int* __restrict__ offs) {
    __shared__ int sh[1024];
    int tid = threadIdx.x;
    int start = tid * 98;
    int end = min(start + 98, NN);
    int sum = 0;
    for (int i = start; i < end; ++i) sum += deg[i];
    sh[tid] = sum;
    __syncthreads();
    for (int off = 1; off < 1024; off <<= 1) {
        int t = (tid >= off) ? sh[tid - off] : 0;
        __syncthreads();
        sh[tid] += t;
        __syncthreads();
    }
    int base = tid ? sh[tid - 1] : 0;
    for (int i = start; i < end; ++i) {
        offs[i] = base;
        base += deg[i];
    }
    if (tid == 1023) offs[NN] = sh[1023];
}

// ---------------- CSR scatter: pack (w:15 | src:17) into one u32 ----------------
__global__ void k_scatter(const int* __restrict__ row, const int* __restrict__ col,
                          const float* __restrict__ dinv, const int* __restrict__ offs,
                          int* __restrict__ cursor, unsigned int* __restrict__ ep) {
    int i = blockIdx.x * 256 + threadIdx.x;
    if (i < EE) {
        int c = col[i], r = row[i];
        int pos = offs[c] + atomicAdd(&cursor[c], 1);
        float w = dinv[r] * dinv[c];  // >= 0
        unsigned int u = __float_as_uint(w);
        unsigned int rb = (u + 0xFFFFu + ((u >> 17) & 1u)) & 0xFFFE0000u;  // RNE @ 7-bit man
        ep[pos] = rb | (unsigned int)r;
    }
}

// ---------------- convert x (fp32 NNx128) -> bf16 NNx128 ----------------
__global__ void k_cvt_x(const float* __restrict__ x, u16* __restrict__ P) {
    int idx = blockIdx.x * 256 + threadIdx.x;
    if (idx >= NN * 32) return;
    float4 v = ((const float4*)x)[idx];
    ushort4 o;
    o.x = f2b(v.x);
    o.y = f2b(v.y);
    o.z = f2b(v.z);
    o.w = f2b(v.w);
    ((ushort4*)P)[idx] = o;
}

// ------- gather propagation, width 128 (bf16), 64 thr/node, 4x edge unroll -------
__global__ void k_prop(const u16* __restrict__ in, int ldin, u16* __restrict__ out, int ldout,
                       const int* __restrict__ offs, const unsigned int* __restrict__ ep) {
    int node = blockIdx.x;
    int f2 = threadIdx.x << 1;
    int s = offs[node], e = offs[node + 1];
    float a0 = 0.f, a1 = 0.f;
    int t = s;
    for (; t + 4 <= e; t += 4) {
        unsigned int p0 = ep[t], p1 = ep[t + 1], p2 = ep[t + 2], p3 = ep[t + 3];
        ushort2 v0 = *(const ushort2*)(in + (size_t)ep_src(p0) * ldin + f2);
        ushort2 v1 = *(const ushort2*)(in + (size_t)ep_src(p1) * ldin + f2);
        ushort2 v2 = *(const ushort2*)(in + (size_t)ep_src(p2) * ldin + f2);
        ushort2 v3 = *(const ushort2*)(in + (size_t)ep_src(p3) * ldin + f2);
        float w0 = ep_w(p0), w1 = ep_w(p1), w2 = ep_w(p2), w3 = ep_w(p3);
        a0 = fmaf(w0, b2f(v0.x), a0);
        a1 = fmaf(w0, b2f(v0.y), a1);
        a0 = fmaf(w1, b2f(v1.x), a0);
        a1 = fmaf(w1, b2f(v1.y), a1);
        a0 = fmaf(w2, b2f(v2.x), a0);
        a1 = fmaf(w2, b2f(v2.y), a1);
        a0 = fmaf(w3, b2f(v3.x), a0);
        a1 = fmaf(w3, b2f(v3.y), a1);
    }
    for (; t < e; ++t) {
        unsigned int p0 = ep[t];
        ushort2 v0 = *(const ushort2*)(in + (size_t)ep_src(p0) * ldin + f2);
        float w0 = ep_w(p0);
        a0 = fmaf(w0, b2f(v0.x), a0);
        a1 = fmaf(w0, b2f(v0.y), a1);
    }
    ushort2 o;
    o.x = f2b(a0);
    o.y = f2b(a1);
    *(ushort2*)(out + (size_t)node * ldout + f2) = o;
}

// -------- width-16 fp32 propagation with addend (Horner), 4x edge unroll --------
__global__ void k_prop16(const float* __restrict__ in, int ldin,
                         const float* __restrict__ add, int ldadd,
                         float* __restrict__ out, const float* __restrict__ bias,
                         const int* __restrict__ offs, const unsigned int* __restrict__ ep) {
    int node = blockIdx.x * 16 + (threadIdx.x >> 4);
    if (node >= NN) return;
    int f = threadIdx.x & 15;
    float acc = add[(size_t)node * ldadd + f];
    int s = offs[node], e = offs[node + 1];
    int t = s;
    for (; t + 4 <= e; t += 4) {
        unsigned int p0 = ep[t], p1 = ep[t + 1], p2 = ep[t + 2], p3 = ep[t + 3];
        float v0 = in[(size_t)ep_src(p0) * ldin + f];
        float v1 = in[(size_t)ep_src(p1) * ldin + f];
        float v2 = in[(size_t)ep_src(p2) * ldin + f];
        float v3 = in[(size_t)ep_src(p3) * ldin + f];
        acc = fmaf(ep_w(p0), v0, acc);
        acc = fmaf(ep_w(p1), v1, acc);
        acc = fmaf(ep_w(p2), v2, acc);
        acc = fmaf(ep_w(p3), v3, acc);
    }
    for (; t < e; ++t) {
        unsigned int p0 = ep[t];
        acc = fmaf(ep_w(p0), in[(size_t)ep_src(p0) * ldin + f], acc);
    }
    if (bias) acc += bias[f];
    out[node * 16 + f] = acc;
}

// ---- MFMA bf16 GEMM, 128x64 tile, two A/B sources (K halves).
// C = [C +] concat(A0,A1) @ concat(B0,B1); A bf16, B fp32 (converted on stage).
// cmode: 0 = write fp32, 1 = write bf16 fresh, 2 = accumulate into bf16 C ----
#define LDS_LD 40  // LDS row stride in elems (16B-aligned rows, conflict-padded)
__global__ __launch_bounds__(256) void k_gemm_mfma(
    const u16* __restrict__ A0, int lda0, const u16* __restrict__ A1, int lda1,
    const float* __restrict__ B0, const float* __restrict__ B1, int ldb,
    void* __restrict__ Cv, int ldc, int M, int Ktot, int Kh,
    const float* __restrict__ bias, int relu, int cmode) {
    __shared__ u16 As[128 * LDS_LD];
    __shared__ u16 Bs[64 * LDS_LD];
    int tid = threadIdx.x;
    int wave = tid >> 6, lane = tid & 63;
    int quad = lane >> 4, lq = lane & 15;
    int m0 = blockIdx.y * 128, n0 = blockIdx.x * 64;
    f32x4 acc[2][4] = {};

    for (int ks = 0; ks < Ktot; ks += 32) {
        const u16* Ap;
        const float* Bp;
        int lda, kk;
        if (ks < Kh) {
            Ap = A0;
            Bp = B0;
            lda = lda0;
            kk = ks;
        } else {
            Ap = A1;
            Bp = B1;
            lda = lda1;
            kk = ks - Kh;
        }
#pragma unroll
        for (int i = 0; i < 2; ++i) {
            int s = tid + i * 256;
            int r = s >> 2, ko = (s & 3) << 3;
            int gr = m0 + r;
            if (gr > M - 1) gr = M - 1;
            uint4 v = *(const uint4*)(Ap + (size_t)gr * lda + kk + ko);
            *(uint4*)&As[r * LDS_LD + ko] = v;
        }
#pragma unroll
        for (int i = 0; i < 2; ++i) {
            int s = tid + i * 256;
            int kr = s >> 4, nq = (s & 15) << 2;
            float4 bv = *(const float4*)(Bp + (size_t)(kk + kr) * ldb + n0 + nq);
            Bs[(nq + 0) * LDS_LD + kr] = f2b(bv.x);
            Bs[(nq + 1) * LDS_LD + kr] = f2b(bv.y);
            Bs[(nq + 2) * LDS_LD + kr] = f2b(bv.z);
            Bs[(nq + 3) * LDS_LD + kr] = f2b(bv.w);
        }
        __syncthreads();
        bf16x8 af[2], bfr[4];
#pragma unroll
        for (int i = 0; i < 2; ++i)
            af[i] = *(bf16x8*)&As[(wave * 32 + i * 16 + lq) * LDS_LD + quad * 8];
#pragma unroll
        for (int j = 0; j < 4; ++j)
            bfr[j] = *(bf16x8*)&Bs[(j * 16 + lq) * LDS_LD + quad * 8];
#pragma unroll
        for (int i = 0; i < 2; ++i)
#pragma unroll
            for (int j = 0; j < 4; ++j)
                acc[i][j] = __builtin_amdgcn_mfma_f32_16x16x32_bf16(af[i], bfr[j], acc[i][j],
                                                                    0, 0, 0);
        __syncthreads();
    }
#pragma unroll
    for (int i = 0; i < 2; ++i) {
#pragma unroll
        for (int j = 0; j < 4; ++j) {
            int c = n0 + j * 16 + lq;
            float bcol = bias ? bias[c] : 0.f;
            int rbase = m0 + wave * 32 + i * 16 + quad * 4;
#pragma unroll
            for (int reg = 0; reg < 4; ++reg) {
                int r = rbase + reg;
                if (r >= M) continue;
                float t = acc[i][j][reg];
                if (cmode == 2) t += b2f(*((u16*)Cv + (size_t)r * ldc + c));
                t += bcol;
                if (relu) t = fmaxf(t, 0.f);
                if (cmode == 0)
                    ((float*)Cv)[(size_t)r * ldc + c] = t;
                else
                    *((u16*)Cv + (size_t)r * ldc + c) = f2b(t);
            }
        }
    }
}

// ---------------- column stats (sum, sumsq) over bf16 NNx512 ----------------
__global__ void k_colstats(const u16* __restrict__ X, int ld, float* __restrict__ stats) {
    int r0 = blockIdx.x * 64;
    int c = threadIdx.x * 2;
    float s0 = 0, s1 = 0, q0 = 0, q1 = 0;
    int rend = min(r0 + 64, NN);
    for (int r = r0; r < rend; ++r) {
        ushort2 v = *(const ushort2*)(X + (size_t)r * ld + c);
        float x0 = b2f(v.x), x1 = b2f(v.y);
        s0 += x0;
        s1 += x1;
        q0 += x0 * x0;
        q1 += x1 * x1;
    }
    atomicAdd(&stats[c], s0);
    atomicAdd(&stats[c + 1], s1);
    atomicAdd(&stats[512 + c], q0);
    atomicAdd(&stats[512 + c + 1], q1);
}

// ---------------- graphnorm apply (in place, bf16) ----------------
__global__ void k_gnorm(u16* __restrict__ X, int ld, const float* __restrict__ stats,
                        const float* __restrict__ w, const float* __restrict__ b,
                        const float* __restrict__ a) {
    int i = blockIdx.x;
    int c = threadIdx.x * 2;
    const float invn = 1.f / NN;
    ushort2 v = *(ushort2*)(X + (size_t)i * ld + c);
    float x0 = b2f(v.x), x1 = b2f(v.y);
    {
        float m = stats[c] * invn, q = stats[512 + c] * invn, al = a[c];
        float var = q - (2.f * al - al * al) * m * m;
        x0 = (x0 - al * m) * rsqrtf(var + EPSF) * w[c] + b[c];
    }
    {
        int c1 = c + 1;
        float m = stats[c1] * invn, q = stats[512 + c1] * invn, al = a[c1];
        float var = q - (2.f * al - al * al) * m * m;
        x1 = (x1 - al * m) * rsqrtf(var + EPSF) * w[c1] + b[c1];
    }
    v.x = f2b(x0);
    v.y = f2b(x1);
    *(ushort2*)(X + (size_t)i * ld + c) = v;
}

// ---------------- repack W3 (4,512,16) -> (512,64) column-concat ----------------
__global__ void k_repackW3(const float* __restrict__ W3, float* __restrict__ W3c) {
    int idx = blockIdx.x * 256 + threadIdx.x;
    if (idx >= 512 * 64) return;
    int kk = idx >> 6, c = idx & 63, k = c >> 4, f = c & 15;
    W3c[idx] = W3[((size_t)k * 512 + kk) * 16 + f];
}

extern "C" void kernel_launch(void* const* d_in, const int* in_sizes, int n_in,
                              void* d_out, int out_size, void* d_ws, size_t ws_size,
                              hipStream_t stream) {
    const float* x = (const float*)d_in[0];
    const int* ei = (const int*)d_in[1];
    const float* W1 = (const float*)d_in[2];
    const float* b1 = (const float*)d_in[3];
    const float* W2 = (const float*)d_in[4];
    const float* b2 = (const float*)d_in[5];
    const float* W3 = (const float*)d_in[6];
    const float* b3 = (const float*)d_in[7];
    const float* g1w = (const float*)d_in[8];
    const float* g1b = (const float*)d_in[9];
    const float* g1a = (const float*)d_in[10];
    const float* g2w = (const float*)d_in[11];
    const float* g2b = (const float*)d_in[12];
    const float* g2a = (const float*)d_in[13];
    const int* row = ei;
    const int* col = ei + EE;

    char* p = (char*)d_ws;
    auto alloc = [&](size_t bytes) {
        char* r = p;
        p += (bytes + 255) & ~(size_t)255;
        return r;
    };
    // Total workspace ~233.4 MiB (below round-4's proven 239.8 MiB)
    u16* H1 = (u16*)alloc((size_t)NN * 512 * 2);         // 102.4 MB
    u16* Y = (u16*)alloc((size_t)NN * 512 * 2);          // 102.4 MB
    u16* X = (u16*)alloc((size_t)NN * 128 * 2);          // 25.6 MB hop ping
    unsigned int* ep = (unsigned int*)alloc((size_t)EE * 4);  // 12.8 MB packed edges
    float* dinv = (float*)alloc((size_t)NN * 4);
    float* W3c = (float*)alloc(512 * 64 * 4);
    float* stats = (float*)alloc(2048 * 4);
    int* deg = (int*)alloc((size_t)NN * 4);
    int* offs = (int*)alloc((size_t)(NN + 1) * 4);
    int* cursor = (int*)alloc((size_t)NN * 4);
    (void)ws_size;
    (void)in_sizes;
    (void)n_in;
    (void)out_size;

    u16* Yp = Y;  // L1 hop scratch region (N x 128, ld 128) inside Y

    // ---- CSR build
    k_init<<<cdiv(NN, 256), 256, 0, stream>>>(deg, cursor, stats);
    k_deg<<<cdiv(EE, 256), 256, 0, stream>>>(col, deg);
    k_dinv<<<cdiv(NN, 256), 256, 0, stream>>>(deg, dinv);
    k_scan<<<1, 1024, 0, stream>>>(deg, offs);
    k_scatter<<<cdiv(EE, 256), 256, 0, stream>>>(row, col, dinv, offs, cursor, ep);

    dim3 gg(512 / 64, cdiv(NN, 128));  // (8, 782)

    // ---- layer 1: H1 = sum_k (A^k x) W1[k]  (hops paired 2-per-GEMM, K=256 each)
    k_cvt_x<<<cdiv(NN * 32, 256), 256, 0, stream>>>(x, X);
    k_prop<<<NN, 64, 0, stream>>>(X, 128, Yp, 128, offs, ep);  // Yp = hop1
    k_gemm_mfma<<<gg, 256, 0, stream>>>(X, 128, Yp, 128, W1, W1 + (size_t)1 * 128 * 512, 512,
                                        H1, 512, NN, 256, 128, nullptr, 0, 1);
    k_prop<<<NN, 64, 0, stream>>>(Yp, 128, X, 128, offs, ep);  // X = hop2
    k_prop<<<NN, 64, 0, stream>>>(X, 128, Yp, 128, offs, ep);  // Yp = hop3
    k_gemm_mfma<<<gg, 256, 0, stream>>>(X, 128, Yp, 128, W1 + (size_t)2 * 128 * 512,
                                        W1 + (size_t)3 * 128 * 512, 512, H1, 512, NN, 256, 128,
                                        b1, 1, 2);
    k_colstats<<<cdiv(NN, 64), 256, 0, stream>>>(H1, 512, stats);
    k_gnorm<<<NN, 256, 0, stream>>>(H1, 512, stats, g1w, g1b, g1a);

    // ---- layer 2: Y = sum_k (A^k h1) W2[k], column-chunked by 128 (4 chunks)
    for (int c = 0; c < 4; ++c) {
        u16* h1c = H1 + 128 * c;                        // ld 512
        const float* W2c = W2 + (size_t)128 * c * 512;  // rows 128c of W2[k] at +k*512*512
        k_prop<<<NN, 64, 0, stream>>>(h1c, 512, X, 128, offs, ep);  // X = hop1
        k_gemm_mfma<<<gg, 256, 0, stream>>>(h1c, 512, X, 128, W2c,
                                            W2c + (size_t)1 * 512 * 512, 512, Y, 512, NN, 256,
                                            128, nullptr, 0, c == 0 ? 1 : 2);
        k_prop<<<NN, 64, 0, stream>>>(X, 128, h1c, 512, offs, ep);  // h1c = hop2
        k_prop<<<NN, 64, 0, stream>>>(h1c, 512, X, 128, offs, ep);  // X = hop3
        k_gemm_mfma<<<gg, 256, 0, stream>>>(h1c, 512, X, 128, W2c + (size_t)2 * 512 * 512,
                                            W2c + (size_t)3 * 512 * 512, 512, Y, 512, NN, 256,
                                            128, (c == 3) ? b2 : nullptr, c == 3 ? 1 : 0, 2);
    }
    k_colstats<<<cdiv(NN, 64), 256, 0, stream>>>(Y, 512, stats + 1024);
    k_gnorm<<<NN, 256, 0, stream>>>(Y, 512, stats + 1024, g2w, g2b, g2a);

    // ---- layer 3 (Horner at width 16): G = h2 @ [W3_0|W3_1|W3_2|W3_3] (fp32, overlays H1)
    float* G = (float*)H1;             // NN x 64 fp32 = 25.6 MB
    float* tA = (float*)X;             // NN x 16 fp32 = 6.4 MB
    float* tB = tA + (size_t)NN * 16;  // X is 25.6 MB, fits both
    k_repackW3<<<cdiv(512 * 64, 256), 256, 0, stream>>>(W3, W3c);
    {
        dim3 g3(1, cdiv(NN, 128));
        k_gemm_mfma<<<g3, 256, 0, stream>>>(Y, 512, Y, 512, W3c, W3c, 64, G, 64, NN, 512, 512,
                                            nullptr, 0, 0);
    }
    k_prop16<<<cdiv(NN, 16), 256, 0, stream>>>(G + 48, 64, G + 32, 64, tA, nullptr, offs, ep);
    k_prop16<<<cdiv(NN, 16), 256, 0, stream>>>(tA, 16, G + 16, 64, tB, nullptr, offs, ep);
    k_prop16<<<cdiv(NN, 16), 256, 0, stream>>>(tB, 16, G + 0, 64, (float*)d_out, b3, offs, ep);
}